// Round 1
// baseline (367.811 us; speedup 1.0000x reference)
//
#include <hip/hip_runtime.h>
#include <hip/hip_bf16.h>
#include <math.h>

#define N_  128
#define D_  512
#define L_  512
#define K_  512
#define M_  (N_*D_)   // 65536

typedef __bf16 bf16x8 __attribute__((ext_vector_type(8)));
typedef float  f32x4  __attribute__((ext_vector_type(4)));

// ---------------------------------------------------------------------------
// Kernel 1: build bf16 DFT basis (Bc/Bs, [k][l] row-major, symmetric) and the
// fp32 per-(d,l) window*scale table W. 512x512 each; double-precision math so
// basis error << bf16 quantization error.
// ---------------------------------------------------------------------------
__global__ void basis_kernel(const float* __restrict__ a,
                             const float* __restrict__ sigma,
                             unsigned short* __restrict__ Bc,
                             unsigned short* __restrict__ Bs,
                             float* __restrict__ W) {
    int idx = blockIdx.x * 256 + threadIdx.x;   // 0 .. 512*512-1
    int r = idx >> 9;    // k (basis) / d (window)
    int c = idx & 511;   // l
    const double w0 = 2.0 * M_PI / 511.0;       // denom = L-1
    double ang = w0 * (double)(r * c);
    __hip_bfloat16 bc = __float2bfloat16((float)cos(ang));
    __hip_bfloat16 bs = __float2bfloat16((float)sin(ang));
    unsigned short uc, us;
    __builtin_memcpy(&uc, &bc, 2);
    __builtin_memcpy(&us, &bs, 2);
    Bc[idx] = uc;
    Bs[idx] = us;
    double cl = cos(w0 * (double)c);
    double av = (double)a[r];
    W[idx] = (float)((av - (1.0 - av) * cl) * exp((double)sigma[r] / 511.0));
}

static __device__ __forceinline__ unsigned pack_bf16x2(float lo, float hi) {
    __hip_bfloat162 h = __float22bfloat162_rn(make_float2(lo, hi));
    unsigned u;
    __builtin_memcpy(&u, &h, 4);
    return u;   // lo in low 16 bits -> memory order [lo, hi]
}

static __device__ __forceinline__ void load_lds_128(const void* g, void* l) {
    __builtin_amdgcn_global_load_lds(
        (const __attribute__((address_space(1))) unsigned int*)g,
        (__attribute__((address_space(3))) unsigned int*)l,
        16, 0, 0);
}

// ---------------------------------------------------------------------------
// Kernel 2: dual-accumulator bf16 MFMA GEMM.
//   A[m][l] = bf16(x[m][l] * W[m%512][l])   (converted on the fly in staging)
//   Cc = A*Bc^T-ish, Cs = A*Bs (B symmetric -> layout-safe)
//   out[m][k] = sqrt(Cc^2 + Cs^2)
// Tile: BM=128, BN=64, BK=32. 4 waves in 2x2. 16 MFMA : 8 ds_read_b128 per
// wave-iter (m97 ratio). B via global_load_lds(16B); A via VGPR fp32*W->bf16.
// ---------------------------------------------------------------------------
__global__ __launch_bounds__(256, 2)
void dft_gemm(const float* __restrict__ x,
              const unsigned short* __restrict__ Bc,
              const unsigned short* __restrict__ Bs,
              const float* __restrict__ W,
              float* __restrict__ out) {
    __shared__ unsigned short sA [128 * 32];  // 8 KB
    __shared__ unsigned short sBc[ 64 * 32];  // 4 KB
    __shared__ unsigned short sBs[ 64 * 32];  // 4 KB

    // supergroup swizzle: 64 consecutive blocks = 8 m-groups x 8 n-groups
    // -> A tiles (2 MB of x) reused 8x while resident in L2/L3.
    const int b  = blockIdx.x;
    const int sg = b >> 6;
    const int ii = b & 63;
    const int mg = sg * 8 + (ii & 7);
    const int ng = ii >> 3;
    const int m0 = mg * 128;
    const int n0 = ng * 64;

    const int tid  = threadIdx.x;
    const int w    = tid >> 6;
    const int lane = tid & 63;

    // ---- A staging coords: thread covers 16 consecutive l of one row ----
    const int ra = tid >> 1;            // 0..127
    const int ca = (tid & 1) * 16;      // 0 or 16
    const float* xp = x + (size_t)(m0 + ra) * L_ + ca;
    const float* wp = W + (size_t)((m0 + ra) & (D_ - 1)) * L_ + ca;
    unsigned short* sAp = &sA[ra * 32 + ca];

    // ---- B staging coords: wave w stages rows [w*16, w*16+16) of each tile
    const int rb = lane >> 2;           // 0..15
    const int cb = (lane & 3) * 8;      // element offset (16B chunks)
    const unsigned short* bcp = Bc + (size_t)(n0 + w * 16 + rb) * L_ + cb;
    const unsigned short* bsp = Bs + (size_t)(n0 + w * 16 + rb) * L_ + cb;
    unsigned short* sBcw = &sBc[w * 512];
    unsigned short* sBsw = &sBs[w * 512];

    const int wm = w >> 1, wn = w & 1;
    const int ml = lane & 15, quad = lane >> 4;

    f32x4 acc_c[4][2], acc_s[4][2];
    const f32x4 zero = {0.f, 0.f, 0.f, 0.f};
#pragma unroll
    for (int mi = 0; mi < 4; ++mi)
#pragma unroll
        for (int ni = 0; ni < 2; ++ni) { acc_c[mi][ni] = zero; acc_s[mi][ni] = zero; }

    for (int kk = 0; kk < L_; kk += 32) {
        // B tiles: async direct-to-LDS (wave-uniform base + lane*16)
        load_lds_128(bcp + kk, sBcw);
        load_lds_128(bsp + kk, sBsw);

        // A tile: fp32 load, window-multiply, pack to bf16, ds_write_b128 x2
        float4 xv0 = *(const float4*)(xp + kk);
        float4 xv1 = *(const float4*)(xp + kk + 4);
        float4 xv2 = *(const float4*)(xp + kk + 8);
        float4 xv3 = *(const float4*)(xp + kk + 12);
        float4 wv0 = *(const float4*)(wp + kk);
        float4 wv1 = *(const float4*)(wp + kk + 4);
        float4 wv2 = *(const float4*)(wp + kk + 8);
        float4 wv3 = *(const float4*)(wp + kk + 12);

        int4 st0, st1;
        st0.x = pack_bf16x2(xv0.x * wv0.x, xv0.y * wv0.y);
        st0.y = pack_bf16x2(xv0.z * wv0.z, xv0.w * wv0.w);
        st0.z = pack_bf16x2(xv1.x * wv1.x, xv1.y * wv1.y);
        st0.w = pack_bf16x2(xv1.z * wv1.z, xv1.w * wv1.w);
        st1.x = pack_bf16x2(xv2.x * wv2.x, xv2.y * wv2.y);
        st1.y = pack_bf16x2(xv2.z * wv2.z, xv2.w * wv2.w);
        st1.z = pack_bf16x2(xv3.x * wv3.x, xv3.y * wv3.y);
        st1.w = pack_bf16x2(xv3.z * wv3.z, xv3.w * wv3.w);
        *(int4*)(sAp)     = st0;
        *(int4*)(sAp + 8) = st1;

        __syncthreads();

        bf16x8 af[4], bcf[2], bsf[2];
#pragma unroll
        for (int mi = 0; mi < 4; ++mi)
            af[mi] = *(const bf16x8*)&sA[(wm * 64 + mi * 16 + ml) * 32 + quad * 8];
#pragma unroll
        for (int ni = 0; ni < 2; ++ni) {
            bcf[ni] = *(const bf16x8*)&sBc[(wn * 32 + ni * 16 + ml) * 32 + quad * 8];
            bsf[ni] = *(const bf16x8*)&sBs[(wn * 32 + ni * 16 + ml) * 32 + quad * 8];
        }
#pragma unroll
        for (int mi = 0; mi < 4; ++mi)
#pragma unroll
            for (int ni = 0; ni < 2; ++ni) {
                acc_c[mi][ni] = __builtin_amdgcn_mfma_f32_16x16x32_bf16(
                    af[mi], bcf[ni], acc_c[mi][ni], 0, 0, 0);
                acc_s[mi][ni] = __builtin_amdgcn_mfma_f32_16x16x32_bf16(
                    af[mi], bsf[ni], acc_s[mi][ni], 0, 0, 0);
            }

        __syncthreads();
    }

    // Epilogue: C/D layout col=lane&15, row=quad*4+reg (m89/m91-verified)
#pragma unroll
    for (int mi = 0; mi < 4; ++mi)
#pragma unroll
        for (int ni = 0; ni < 2; ++ni) {
#pragma unroll
            for (int r = 0; r < 4; ++r) {
                float cv = acc_c[mi][ni][r];
                float sv = acc_s[mi][ni][r];
                int row = m0 + wm * 64 + mi * 16 + quad * 4 + r;
                int col = n0 + wn * 32 + ni * 16 + ml;
                out[(size_t)row * K_ + col] = sqrtf(cv * cv + sv * sv);
            }
        }
}

extern "C" void kernel_launch(void* const* d_in, const int* in_sizes, int n_in,
                              void* d_out, int out_size, void* d_ws, size_t ws_size,
                              hipStream_t stream) {
    (void)in_sizes; (void)n_in; (void)out_size; (void)ws_size;
    const float* x     = (const float*)d_in[0];
    const float* a     = (const float*)d_in[1];
    const float* sigma = (const float*)d_in[2];
    float* out = (float*)d_out;

    // workspace layout: Bc (512KB bf16) | Bs (512KB bf16) | W (1MB fp32)
    unsigned short* Bc = (unsigned short*)d_ws;
    unsigned short* Bs = Bc + 512 * 512;
    float*          W  = (float*)(Bs + 512 * 512);

    basis_kernel<<<dim3(1024), dim3(256), 0, stream>>>(a, sigma, Bc, Bs, W);
    dft_gemm<<<dim3(4096), dim3(256), 0, stream>>>(x, Bc, Bs, W, out);
}

// Round 2
// 308.657 us; speedup vs baseline: 1.1916x; 1.1916x over previous
//
#include <hip/hip_runtime.h>
#include <hip/hip_bf16.h>
#include <math.h>

#define N_  128
#define D_  512
#define L_  512
#define K_  512
#define M_  (N_*D_)   // 65536

typedef __bf16 bf16x8 __attribute__((ext_vector_type(8)));
typedef float  f32x4  __attribute__((ext_vector_type(4)));
typedef unsigned short ushort_t;

// ---------------------------------------------------------------------------
// Kernel 1: bf16 DFT basis + fp32 window table. FAST version: the basis is
// exactly periodic in (k*l mod 511), so reduce in integers and use fp32
// sincos on [0, 2pi) — error << bf16 quantization.
// ---------------------------------------------------------------------------
__global__ void basis_kernel(const float* __restrict__ a,
                             const float* __restrict__ sigma,
                             ushort_t* __restrict__ Bc,
                             ushort_t* __restrict__ Bs,
                             float* __restrict__ W) {
    int idx = blockIdx.x * 256 + threadIdx.x;   // 0 .. 512*512-1
    int r = idx >> 9;    // k (basis) / d (window)
    int c = idx & 511;   // l
    unsigned prod = (unsigned)(r * c);
    unsigned m = prod % 511u;                   // exact periodic reduction
    const float w0 = 6.283185307179586f / 511.0f;
    float sn, cs;
    sincosf((float)m * w0, &sn, &cs);
    __hip_bfloat16 bc = __float2bfloat16(cs);
    __hip_bfloat16 bs = __float2bfloat16(sn);
    ushort_t uc, us;
    __builtin_memcpy(&uc, &bc, 2);
    __builtin_memcpy(&us, &bs, 2);
    Bc[idx] = uc;
    Bs[idx] = us;
    float cl = cosf((float)c * w0);
    float av = a[r];
    W[idx] = (av - (1.0f - av) * cl) * expf(sigma[r] * (1.0f / 511.0f));
}

static __device__ __forceinline__ unsigned pack_bf16x2(float lo, float hi) {
    __hip_bfloat162 h = __float22bfloat162_rn(make_float2(lo, hi));
    unsigned u;
    __builtin_memcpy(&u, &h, 4);
    return u;   // lo in low 16 bits -> memory order [lo, hi]
}

static __device__ __forceinline__ void load_lds_128(const void* g, void* l) {
    __builtin_amdgcn_global_load_lds(
        (const __attribute__((address_space(1))) unsigned int*)g,
        (__attribute__((address_space(3))) unsigned int*)l,
        16, 0, 0);
}

// ---------------------------------------------------------------------------
// Kernel 2 (fast path): materialize xw[m][l] = bf16(x[m][l] * W[m%512][l]).
// Each thread handles 16 elements (one 64B x segment, 32B bf16 out).
// ---------------------------------------------------------------------------
__global__ void prep_kernel(const float* __restrict__ x,
                            const float* __restrict__ W,
                            ushort_t* __restrict__ xw) {
    size_t t  = (size_t)blockIdx.x * 256 + threadIdx.x;
    size_t e0 = t * 16;
    int mrow = (int)(e0 >> 9);
    int l    = (int)(e0 & 511);
    const float* xp = x + e0;
    const float* wp = W + ((size_t)(mrow & (D_ - 1)) << 9) + l;
    float4 x0 = *(const float4*)(xp + 0);
    float4 x1 = *(const float4*)(xp + 4);
    float4 x2 = *(const float4*)(xp + 8);
    float4 x3 = *(const float4*)(xp + 12);
    float4 w0 = *(const float4*)(wp + 0);
    float4 w1 = *(const float4*)(wp + 4);
    float4 w2 = *(const float4*)(wp + 8);
    float4 w3 = *(const float4*)(wp + 12);
    int4 s0, s1;
    s0.x = pack_bf16x2(x0.x * w0.x, x0.y * w0.y);
    s0.y = pack_bf16x2(x0.z * w0.z, x0.w * w0.w);
    s0.z = pack_bf16x2(x1.x * w1.x, x1.y * w1.y);
    s0.w = pack_bf16x2(x1.z * w1.z, x1.w * w1.w);
    s1.x = pack_bf16x2(x2.x * w2.x, x2.y * w2.y);
    s1.y = pack_bf16x2(x2.z * w2.z, x2.w * w2.w);
    s1.z = pack_bf16x2(x3.x * w3.x, x3.y * w3.y);
    s1.w = pack_bf16x2(x3.z * w3.z, x3.w * w3.w);
    *(int4*)(xw + e0)     = s0;
    *(int4*)(xw + e0 + 8) = s1;
}

// ---------------------------------------------------------------------------
// Kernel 3 (fast path): pure global_load_lds dual-accumulator GEMM (m97-style).
// Tile BM=128, BN=64, BK=32; 4 waves 2x2. All staging via global_load_lds
// width=16 with an XOR-swizzled 16B-chunk layout to kill LDS bank conflicts:
//   logical chunk q of row r lives at physical chunk q ^ ((r>>1)&3).
// ---------------------------------------------------------------------------
__global__ __launch_bounds__(256, 4)
void dft_gemm_fast(const ushort_t* __restrict__ xw,
                   const ushort_t* __restrict__ Bc,
                   const ushort_t* __restrict__ Bs,
                   float* __restrict__ out) {
    __shared__ ushort_t sA [128 * 32];  // 8 KB
    __shared__ ushort_t sBc[ 64 * 32];  // 4 KB
    __shared__ ushort_t sBs[ 64 * 32];  // 4 KB

    const int b  = blockIdx.x;
    const int sg = b >> 6;
    const int ii = b & 63;
    const int mg = sg * 8 + (ii & 7);
    const int ng = ii >> 3;
    const int m0 = mg * 128;
    const int n0 = ng * 64;

    const int tid  = threadIdx.x;
    const int w    = tid >> 6;
    const int lane = tid & 63;

    // --- A staging: 2 issues x 256 threads x 16B cover 128x32 bf16 (8KB) ---
    // issue i: flat chunk fc = i*256 + tid; row = fc>>2, phys chunk = fc&3,
    // logical chunk q = pc ^ ((row>>1)&3)  (source-side swizzle)
    const int rA0 = tid >> 2;
    const int qA0 = (tid & 3) ^ ((rA0 >> 1) & 3);
    const int rA1 = (256 + tid) >> 2;
    const int qA1 = (tid & 3) ^ ((rA1 >> 1) & 3);
    const ushort_t* aSrc0 = xw + (size_t)(m0 + rA0) * L_ + qA0 * 8;
    const ushort_t* aSrc1 = xw + (size_t)(m0 + rA1) * L_ + qA1 * 8;
    ushort_t* aDst0 = &sA[w * 512];          // bytes: w*1024
    ushort_t* aDst1 = &sA[2048 + w * 512];   // bytes: 4096 + w*1024

    // --- B staging: 1 issue each covers 64x32 bf16 (4KB) ---
    const int rB = tid >> 2;
    const int qB = (tid & 3) ^ ((rB >> 1) & 3);
    const ushort_t* bcSrc = Bc + (size_t)(n0 + rB) * L_ + qB * 8;
    const ushort_t* bsSrc = Bs + (size_t)(n0 + rB) * L_ + qB * 8;
    ushort_t* bcDst = &sBc[w * 512];
    ushort_t* bsDst = &sBs[w * 512];

    const int wm = w >> 1, wn = w & 1;
    const int ml = lane & 15, quad = lane >> 4;

    // precompute swizzled LDS read offsets (in shorts)
    int aOff[4], bOff[2];
#pragma unroll
    for (int mi = 0; mi < 4; ++mi) {
        int ar = wm * 64 + mi * 16 + ml;
        int pc = quad ^ ((ar >> 1) & 3);
        aOff[mi] = ar * 32 + pc * 8;
    }
#pragma unroll
    for (int ni = 0; ni < 2; ++ni) {
        int br = wn * 32 + ni * 16 + ml;
        int pc = quad ^ ((br >> 1) & 3);
        bOff[ni] = br * 32 + pc * 8;
    }

    f32x4 acc_c[4][2], acc_s[4][2];
    const f32x4 zero = {0.f, 0.f, 0.f, 0.f};
#pragma unroll
    for (int mi = 0; mi < 4; ++mi)
#pragma unroll
        for (int ni = 0; ni < 2; ++ni) { acc_c[mi][ni] = zero; acc_s[mi][ni] = zero; }

    for (int kk = 0; kk < L_; kk += 32) {
        load_lds_128(aSrc0 + kk, aDst0);
        load_lds_128(aSrc1 + kk, aDst1);
        load_lds_128(bcSrc + kk, bcDst);
        load_lds_128(bsSrc + kk, bsDst);

        __syncthreads();

        bf16x8 af[4], bcf[2], bsf[2];
#pragma unroll
        for (int mi = 0; mi < 4; ++mi)
            af[mi] = *(const bf16x8*)&sA[aOff[mi]];
#pragma unroll
        for (int ni = 0; ni < 2; ++ni) {
            bcf[ni] = *(const bf16x8*)&sBc[bOff[ni]];
            bsf[ni] = *(const bf16x8*)&sBs[bOff[ni]];
        }
#pragma unroll
        for (int mi = 0; mi < 4; ++mi)
#pragma unroll
            for (int ni = 0; ni < 2; ++ni) {
                acc_c[mi][ni] = __builtin_amdgcn_mfma_f32_16x16x32_bf16(
                    af[mi], bcf[ni], acc_c[mi][ni], 0, 0, 0);
                acc_s[mi][ni] = __builtin_amdgcn_mfma_f32_16x16x32_bf16(
                    af[mi], bsf[ni], acc_s[mi][ni], 0, 0, 0);
            }

        __syncthreads();
    }

#pragma unroll
    for (int mi = 0; mi < 4; ++mi)
#pragma unroll
        for (int ni = 0; ni < 2; ++ni) {
#pragma unroll
            for (int r = 0; r < 4; ++r) {
                float cv = acc_c[mi][ni][r];
                float sv = acc_s[mi][ni][r];
                int row = m0 + wm * 64 + mi * 16 + quad * 4 + r;
                int col = n0 + wn * 32 + ni * 16 + ml;
                out[(size_t)row * K_ + col] = sqrtf(cv * cv + sv * sv);
            }
        }
}

// ---------------------------------------------------------------------------
// Fallback GEMM (round-1, fused VGPR staging) — used only if ws too small.
// ---------------------------------------------------------------------------
__global__ __launch_bounds__(256, 2)
void dft_gemm_fused(const float* __restrict__ x,
                    const ushort_t* __restrict__ Bc,
                    const ushort_t* __restrict__ Bs,
                    const float* __restrict__ W,
                    float* __restrict__ out) {
    __shared__ ushort_t sA [128 * 32];
    __shared__ ushort_t sBc[ 64 * 32];
    __shared__ ushort_t sBs[ 64 * 32];

    const int b  = blockIdx.x;
    const int sg = b >> 6;
    const int ii = b & 63;
    const int mg = sg * 8 + (ii & 7);
    const int ng = ii >> 3;
    const int m0 = mg * 128;
    const int n0 = ng * 64;

    const int tid  = threadIdx.x;
    const int w    = tid >> 6;
    const int lane = tid & 63;

    const int ra = tid >> 1;
    const int ca = (tid & 1) * 16;
    const float* xp = x + (size_t)(m0 + ra) * L_ + ca;
    const float* wp = W + (size_t)((m0 + ra) & (D_ - 1)) * L_ + ca;
    ushort_t* sAp = &sA[ra * 32 + ca];

    const int rb = lane >> 2;
    const int cb = (lane & 3) * 8;
    const ushort_t* bcp = Bc + (size_t)(n0 + w * 16 + rb) * L_ + cb;
    const ushort_t* bsp = Bs + (size_t)(n0 + w * 16 + rb) * L_ + cb;
    ushort_t* sBcw = &sBc[w * 512];
    ushort_t* sBsw = &sBs[w * 512];

    const int wm = w >> 1, wn = w & 1;
    const int ml = lane & 15, quad = lane >> 4;

    f32x4 acc_c[4][2], acc_s[4][2];
    const f32x4 zero = {0.f, 0.f, 0.f, 0.f};
#pragma unroll
    for (int mi = 0; mi < 4; ++mi)
#pragma unroll
        for (int ni = 0; ni < 2; ++ni) { acc_c[mi][ni] = zero; acc_s[mi][ni] = zero; }

    for (int kk = 0; kk < L_; kk += 32) {
        load_lds_128(bcp + kk, sBcw);
        load_lds_128(bsp + kk, sBsw);

        float4 xv0 = *(const float4*)(xp + kk);
        float4 xv1 = *(const float4*)(xp + kk + 4);
        float4 xv2 = *(const float4*)(xp + kk + 8);
        float4 xv3 = *(const float4*)(xp + kk + 12);
        float4 wv0 = *(const float4*)(wp + kk);
        float4 wv1 = *(const float4*)(wp + kk + 4);
        float4 wv2 = *(const float4*)(wp + kk + 8);
        float4 wv3 = *(const float4*)(wp + kk + 12);

        int4 st0, st1;
        st0.x = pack_bf16x2(xv0.x * wv0.x, xv0.y * wv0.y);
        st0.y = pack_bf16x2(xv0.z * wv0.z, xv0.w * wv0.w);
        st0.z = pack_bf16x2(xv1.x * wv1.x, xv1.y * wv1.y);
        st0.w = pack_bf16x2(xv1.z * wv1.z, xv1.w * wv1.w);
        st1.x = pack_bf16x2(xv2.x * wv2.x, xv2.y * wv2.y);
        st1.y = pack_bf16x2(xv2.z * wv2.z, xv2.w * wv2.w);
        st1.z = pack_bf16x2(xv3.x * wv3.x, xv3.y * wv3.y);
        st1.w = pack_bf16x2(xv3.z * wv3.z, xv3.w * wv3.w);
        *(int4*)(sAp)     = st0;
        *(int4*)(sAp + 8) = st1;

        __syncthreads();

        bf16x8 af[4], bcf[2], bsf[2];
#pragma unroll
        for (int mi = 0; mi < 4; ++mi)
            af[mi] = *(const bf16x8*)&sA[(wm * 64 + mi * 16 + ml) * 32 + quad * 8];
#pragma unroll
        for (int ni = 0; ni < 2; ++ni) {
            bcf[ni] = *(const bf16x8*)&sBc[(wn * 32 + ni * 16 + ml) * 32 + quad * 8];
            bsf[ni] = *(const bf16x8*)&sBs[(wn * 32 + ni * 16 + ml) * 32 + quad * 8];
        }
#pragma unroll
        for (int mi = 0; mi < 4; ++mi)
#pragma unroll
            for (int ni = 0; ni < 2; ++ni) {
                acc_c[mi][ni] = __builtin_amdgcn_mfma_f32_16x16x32_bf16(
                    af[mi], bcf[ni], acc_c[mi][ni], 0, 0, 0);
                acc_s[mi][ni] = __builtin_amdgcn_mfma_f32_16x16x32_bf16(
                    af[mi], bsf[ni], acc_s[mi][ni], 0, 0, 0);
            }

        __syncthreads();
    }

#pragma unroll
    for (int mi = 0; mi < 4; ++mi)
#pragma unroll
        for (int ni = 0; ni < 2; ++ni) {
#pragma unroll
            for (int r = 0; r < 4; ++r) {
                float cv = acc_c[mi][ni][r];
                float sv = acc_s[mi][ni][r];
                int row = m0 + wm * 64 + mi * 16 + quad * 4 + r;
                int col = n0 + wn * 32 + ni * 16 + ml;
                out[(size_t)row * K_ + col] = sqrtf(cv * cv + sv * sv);
            }
        }
}

extern "C" void kernel_launch(void* const* d_in, const int* in_sizes, int n_in,
                              void* d_out, int out_size, void* d_ws, size_t ws_size,
                              hipStream_t stream) {
    (void)in_sizes; (void)n_in; (void)out_size;
    const float* x     = (const float*)d_in[0];
    const float* a     = (const float*)d_in[1];
    const float* sigma = (const float*)d_in[2];
    float* out = (float*)d_out;

    // workspace: Bc (512KB) | Bs (512KB) | W (1MB) | xw (67.1MB, fast path)
    ushort_t* Bc = (ushort_t*)d_ws;
    ushort_t* Bs = Bc + 512 * 512;
    float*    W  = (float*)(Bs + 512 * 512);
    ushort_t* xw = (ushort_t*)(W + 512 * 512);

    const size_t need = (size_t)512 * 512 * 2 * 2 + (size_t)512 * 512 * 4
                      + (size_t)M_ * L_ * 2;

    basis_kernel<<<dim3(1024), dim3(256), 0, stream>>>(a, sigma, Bc, Bs, W);

    if (ws_size >= need) {
        prep_kernel<<<dim3(8192), dim3(256), 0, stream>>>(x, W, xw);
        dft_gemm_fast<<<dim3(4096), dim3(256), 0, stream>>>(xw, Bc, Bs, out);
    } else {
        dft_gemm_fused<<<dim3(4096), dim3(256), 0, stream>>>(x, Bc, Bs, W, out);
    }
}

// Round 4
// 304.918 us; speedup vs baseline: 1.2063x; 1.0123x over previous
//
#include <hip/hip_runtime.h>
#include <hip/hip_bf16.h>
#include <math.h>

#define N_  128
#define D_  512
#define L_  512
#define K_  512
#define M_  (N_*D_)   // 65536

typedef __bf16 bf16x8 __attribute__((ext_vector_type(8)));
typedef float  f32x4  __attribute__((ext_vector_type(4)));
typedef unsigned short ushort_t;

// ---------------------------------------------------------------------------
// Kernel 1: bf16 DFT basis (Bc/Bs, [k][l], symmetric) + separable window
// tables: W[d,l] = P[d] + Q[d]*C[l],  P=a*e, Q=-(1-a)*e, e=exp(sigma/511),
// C[l]=cos(2*pi*l/511). Basis reduced exactly via (k*l mod 511), fp32 sincos.
// ---------------------------------------------------------------------------
__global__ void basis_kernel(const float* __restrict__ a,
                             const float* __restrict__ sigma,
                             ushort_t* __restrict__ Bc,
                             ushort_t* __restrict__ Bs,
                             float* __restrict__ P,
                             float* __restrict__ Q,
                             float* __restrict__ C) {
    int idx = blockIdx.x * 256 + threadIdx.x;   // 0 .. 512*512-1
    int r = idx >> 9;    // k
    int c = idx & 511;   // l
    unsigned m = (unsigned)(r * c) % 511u;      // exact periodic reduction
    const float w0 = 6.283185307179586f / 511.0f;
    float sn, cs;
    sincosf((float)m * w0, &sn, &cs);
    __hip_bfloat16 bc = __float2bfloat16(cs);
    __hip_bfloat16 bs = __float2bfloat16(sn);
    ushort_t uc, us;
    __builtin_memcpy(&uc, &bc, 2);
    __builtin_memcpy(&us, &bs, 2);
    Bc[idx] = uc;
    Bs[idx] = us;
    if (idx < 512) {
        float e = expf(sigma[idx] * (1.0f / 511.0f));
        P[idx] = a[idx] * e;
        Q[idx] = -(1.0f - a[idx]) * e;
        C[idx] = cosf((float)idx * w0);
    }
}

static __device__ __forceinline__ unsigned pack_bf16x2(float lo, float hi) {
    __hip_bfloat162 h = __float22bfloat162_rn(make_float2(lo, hi));
    unsigned u;
    __builtin_memcpy(&u, &h, 4);
    return u;   // lo in low 16 bits -> memory order [lo, hi]
}

static __device__ __forceinline__ void load_lds_128(const void* g, void* l) {
    __builtin_amdgcn_global_load_lds(
        (const __attribute__((address_space(1))) unsigned int*)g,
        (__attribute__((address_space(3))) unsigned int*)l,
        16, 0, 0);
}

// ---------------------------------------------------------------------------
// Kernel 2: xw[m][l] = bf16(x[m][l] * (P[d] + Q[d]*C[l])), d = m%512.
// One float4 per thread, consecutive lanes -> consecutive 16B reads / 8B
// writes. 33,554,432 floats / 4 per thread = 8,388,608 threads = 32768 blocks.
// ---------------------------------------------------------------------------
__global__ void prep_kernel(const float* __restrict__ x,
                            const float* __restrict__ P,
                            const float* __restrict__ Q,
                            const float* __restrict__ C,
                            ushort_t* __restrict__ xw) {
    int t = blockIdx.x * 256 + threadIdx.x;     // 0 .. 8388607
    size_t e0 = (size_t)t * 4;
    int row = t >> 7;            // m-row (512 floats = 128 float4 per row)
    int li  = t & 127;           // float4 index within row
    int d   = row & (D_ - 1);
    float4 xv = *(const float4*)(x + e0);
    float4 cv = *(const float4*)(C + li * 4);
    float p = P[d], q = Q[d];
    float w0v = fmaf(q, cv.x, p);
    float w1v = fmaf(q, cv.y, p);
    float w2v = fmaf(q, cv.z, p);
    float w3v = fmaf(q, cv.w, p);
    int2 s;
    s.x = (int)pack_bf16x2(xv.x * w0v, xv.y * w1v);
    s.y = (int)pack_bf16x2(xv.z * w2v, xv.w * w3v);
    *(int2*)(xw + e0) = s;
}

// ---------------------------------------------------------------------------
// Kernel 3: dual-accumulator bf16 MFMA GEMM, BM=128 BN=128 BK=32, 4 waves 2x2
// (each wave 64x64 per trig branch). All staging via global_load_lds(16B)
// with XOR 16B-chunk swizzle (zero bank conflicts, verified round 2).
// Per wave-iter: 32 MFMA : 12 ds_read_b128.
// ---------------------------------------------------------------------------
__global__ __launch_bounds__(256, 2)
void dft_gemm3(const ushort_t* __restrict__ xw,
               const ushort_t* __restrict__ Bc,
               const ushort_t* __restrict__ Bs,
               float* __restrict__ out) {
    __shared__ ushort_t sA [128 * 32];  // 8 KB
    __shared__ ushort_t sBc[128 * 32];  // 8 KB
    __shared__ ushort_t sBs[128 * 32];  // 8 KB

    const int b  = blockIdx.x;          // 2048 blocks
    const int ng = b & 3;
    const int mg = b >> 2;
    const int m0 = mg * 128;
    const int n0 = ng * 128;

    const int tid  = threadIdx.x;
    const int w    = tid >> 6;
    const int lane = tid & 63;

    // --- staging: tile = 512 x 16B chunks; 2 issues per buffer per thread ---
    // chunk fc -> row = fc>>2, phys chunk pc = fc&3, logical q = pc^((row>>1)&3)
    const int r0 = tid >> 2;
    const int q0 = (tid & 3) ^ ((r0 >> 1) & 3);
    const int r1 = (256 + tid) >> 2;
    const int q1 = ((256 + tid) & 3) ^ ((r1 >> 1) & 3);

    const ushort_t* aS0  = xw + (size_t)(m0 + r0) * L_ + q0 * 8;
    const ushort_t* aS1  = xw + (size_t)(m0 + r1) * L_ + q1 * 8;
    const ushort_t* bcS0 = Bc + (size_t)(n0 + r0) * L_ + q0 * 8;
    const ushort_t* bcS1 = Bc + (size_t)(n0 + r1) * L_ + q1 * 8;
    const ushort_t* bsS0 = Bs + (size_t)(n0 + r0) * L_ + q0 * 8;
    const ushort_t* bsS1 = Bs + (size_t)(n0 + r1) * L_ + q1 * 8;

    ushort_t* aD0  = &sA [w * 512];
    ushort_t* aD1  = &sA [2048 + w * 512];
    ushort_t* bcD0 = &sBc[w * 512];
    ushort_t* bcD1 = &sBc[2048 + w * 512];
    ushort_t* bsD0 = &sBs[w * 512];
    ushort_t* bsD1 = &sBs[2048 + w * 512];

    const int wm = w >> 1, wn = w & 1;
    const int ml = lane & 15, quad = lane >> 4;

    int aOff[4], bOff[4];
#pragma unroll
    for (int mi = 0; mi < 4; ++mi) {
        int ar = wm * 64 + mi * 16 + ml;
        int pc = quad ^ ((ar >> 1) & 3);
        aOff[mi] = ar * 32 + pc * 8;
    }
#pragma unroll
    for (int ni = 0; ni < 4; ++ni) {
        int br = wn * 64 + ni * 16 + ml;
        int pc = quad ^ ((br >> 1) & 3);
        bOff[ni] = br * 32 + pc * 8;
    }

    f32x4 acc_c[4][4], acc_s[4][4];
    const f32x4 zero = {0.f, 0.f, 0.f, 0.f};
#pragma unroll
    for (int mi = 0; mi < 4; ++mi)
#pragma unroll
        for (int ni = 0; ni < 4; ++ni) { acc_c[mi][ni] = zero; acc_s[mi][ni] = zero; }

    for (int kk = 0; kk < L_; kk += 32) {
        load_lds_128(aS0  + kk, aD0);
        load_lds_128(aS1  + kk, aD1);
        load_lds_128(bcS0 + kk, bcD0);
        load_lds_128(bcS1 + kk, bcD1);
        load_lds_128(bsS0 + kk, bsD0);
        load_lds_128(bsS1 + kk, bsD1);

        __syncthreads();

        bf16x8 af[4], bcf[4], bsf[4];
#pragma unroll
        for (int mi = 0; mi < 4; ++mi)
            af[mi] = *(const bf16x8*)&sA[aOff[mi]];
#pragma unroll
        for (int ni = 0; ni < 4; ++ni) {
            bcf[ni] = *(const bf16x8*)&sBc[bOff[ni]];
            bsf[ni] = *(const bf16x8*)&sBs[bOff[ni]];
        }
#pragma unroll
        for (int mi = 0; mi < 4; ++mi)
#pragma unroll
            for (int ni = 0; ni < 4; ++ni) {
                acc_c[mi][ni] = __builtin_amdgcn_mfma_f32_16x16x32_bf16(
                    af[mi], bcf[ni], acc_c[mi][ni], 0, 0, 0);
                acc_s[mi][ni] = __builtin_amdgcn_mfma_f32_16x16x32_bf16(
                    af[mi], bsf[ni], acc_s[mi][ni], 0, 0, 0);
            }

        __syncthreads();
    }

    // C/D layout: col = lane&15, row = quad*4 + reg (m89/m91-verified)
#pragma unroll
    for (int mi = 0; mi < 4; ++mi)
#pragma unroll
        for (int ni = 0; ni < 4; ++ni) {
#pragma unroll
            for (int r = 0; r < 4; ++r) {
                float cv = acc_c[mi][ni][r];
                float sv = acc_s[mi][ni][r];
                int row = m0 + wm * 64 + mi * 16 + quad * 4 + r;
                int col = n0 + wn * 64 + ni * 16 + ml;
                out[(size_t)row * K_ + col] = sqrtf(cv * cv + sv * sv);
            }
        }
}

extern "C" void kernel_launch(void* const* d_in, const int* in_sizes, int n_in,
                              void* d_out, int out_size, void* d_ws, size_t ws_size,
                              hipStream_t stream) {
    (void)in_sizes; (void)n_in; (void)out_size; (void)ws_size;
    const float* x     = (const float*)d_in[0];
    const float* a     = (const float*)d_in[1];
    const float* sigma = (const float*)d_in[2];
    float* out = (float*)d_out;

    // ws: Bc (512KB) | Bs (512KB) | P (2KB) | Q (2KB) | C (2KB) | xw (67.1MB)
    ushort_t* Bc = (ushort_t*)d_ws;
    ushort_t* Bs = Bc + 512 * 512;
    float*    P  = (float*)(Bs + 512 * 512);
    float*    Q  = P + 512;
    float*    C  = Q + 512;
    ushort_t* xw = (ushort_t*)(C + 512);

    basis_kernel<<<dim3(1024), dim3(256), 0, stream>>>(a, sigma, Bc, Bs, P, Q, C);
    prep_kernel<<<dim3(32768), dim3(256), 0, stream>>>(x, P, Q, C, xw);
    dft_gemm3<<<dim3(2048), dim3(256), 0, stream>>>(xw, Bc, Bs, out);
}